// Round 1
// baseline (686.160 us; speedup 1.0000x reference)
//
#include <hip/hip_runtime.h>

// out[i][j] = (sd[i][j] < 5 ? 1 : 0)
//           * (lbl[i]==lbl[j] ? 1.0 : 0.1)
//           * exp(-(sd^2 + dtw^2))        // fused: exp(-sd^2)*exp(-dtw^2)
//
// N = 8192, all matrices float32. adj_mx (d_in[0]) is UNUSED by the
// reference output -> never read it (saves 256 MB of HBM traffic).

#define N_DIM 8192
#define N_SHIFT 13            // log2(8192)
#define DTW_DELTA 5.0f
#define EPS_CLU 0.1f

__global__ __launch_bounds__(256) void dtw_mask_kernel(
    const float* __restrict__ sd,
    const float* __restrict__ dtw,
    const int*   __restrict__ lbl,
    float*       __restrict__ out)
{
    const long long nvec = (long long)N_DIM * N_DIM / 4;   // float4 count
    long long idx    = (long long)blockIdx.x * blockDim.x + threadIdx.x;
    const long long stride = (long long)gridDim.x * blockDim.x;

    const float4* __restrict__ sd4  = (const float4*)sd;
    const float4* __restrict__ dtw4 = (const float4*)dtw;
    const int4*   __restrict__ lbl4 = (const int4*)lbl;
    float4* __restrict__ out4 = (float4*)out;

    for (; idx < nvec; idx += stride) {
        const long long e = idx << 2;             // element index of .x
        const int row = (int)(e >> N_SHIFT);      // i
        const int col = (int)(e & (N_DIM - 1));   // j of .x  (multiple of 4)

        float4 s = sd4[idx];
        float4 d = dtw4[idx];
        const int  li = lbl[row];                 // wave-uniform -> L1 broadcast
        const int4 lj = lbl4[col >> 2];

        float4 o;
        {
            float g = __expf(-(s.x * s.x + d.x * d.x));
            o.x = (s.x < DTW_DELTA) ? ((li == lj.x) ? g : EPS_CLU * g) : 0.0f;
        }
        {
            float g = __expf(-(s.y * s.y + d.y * d.y));
            o.y = (s.y < DTW_DELTA) ? ((li == lj.y) ? g : EPS_CLU * g) : 0.0f;
        }
        {
            float g = __expf(-(s.z * s.z + d.z * d.z));
            o.z = (s.z < DTW_DELTA) ? ((li == lj.z) ? g : EPS_CLU * g) : 0.0f;
        }
        {
            float g = __expf(-(s.w * s.w + d.w * d.w));
            o.w = (s.w < DTW_DELTA) ? ((li == lj.w) ? g : EPS_CLU * g) : 0.0f;
        }
        out4[idx] = o;
    }
}

extern "C" void kernel_launch(void* const* d_in, const int* in_sizes, int n_in,
                              void* d_out, int out_size, void* d_ws, size_t ws_size,
                              hipStream_t stream)
{
    // setup_inputs order: adj_mx, sd_mx, dtw_matrix, cluster_labels
    const float* sd  = (const float*)d_in[1];
    const float* dtw = (const float*)d_in[2];
    const int*   lbl = (const int*)d_in[3];
    float* out = (float*)d_out;

    const long long nvec = (long long)N_DIM * N_DIM / 4;   // 16.7M float4s
    const int block = 256;
    // ~4 float4s per thread: 16384 blocks x 256 threads
    int grid = (int)((nvec / 4 + block - 1) / block);
    dtw_mask_kernel<<<grid, block, 0, stream>>>(sd, dtw, lbl, out);
}